// Round 5
// baseline (123.058 us; speedup 1.0000x reference)
//
#include <hip/hip_runtime.h>

typedef unsigned short u16;
typedef unsigned int u32;
typedef unsigned long long u64;

#define VOCAB 50000
#define BATCH 2048
#define NTOP 64
#define RHO 0.1f

#define KSPLIT 4
#define CHUNKA 12512        // 391*32; chunks: 0,12512,25024,37536; last covers 12464
#define KSTEP 256
#define NSTEPS 49           // ceil(12512/256); uniform across chunks
#define NKB 1568            // bp 32-k blocks covering 50176 (zero-padded past 50000)
#define GPC 12544           // 50176/4 float4-groups per topic row

typedef short bf16x4 __attribute__((ext_vector_type(4)));
typedef short bf16x8 __attribute__((ext_vector_type(8)));
typedef float f32x4 __attribute__((ext_vector_type(4)));

__device__ __forceinline__ u16 f32_to_bf16(float f) {
  u32 u = __builtin_bit_cast(u32, f);
  return (u16)((u + 0x8000u) >> 16);
}
__device__ __forceinline__ u32 pack2(float a, float b) {
  return (u32)f32_to_bf16(a) | ((u32)f32_to_bf16(b) << 16);
}
__device__ __forceinline__ u32 cvtpk(float lo, float hi) {
  u32 r;
  asm volatile("v_cvt_pk_bf16_f32 %0, %1, %2" : "=v"(r) : "v"(lo), "v"(hi));
  return r;
}
union frag_cast { bf16x4 h[2]; bf16x8 v; };

// Kernel 1: permute beta f32 -> bf16 MFMA-fragment order (R2-proven layout):
// element(bp) = kb*2048 + col*32 + p;  p = fk*8 + e, e<4 -> k=kb*32+fk*4+e,
// e>=4 -> k=kb*32+16+fk*4+(e-4). Zero-padded for k in [50000, 50176).
__global__ void ctm_prep(const float* __restrict__ beta, u16* __restrict__ bp) {
  int i = blockIdx.x * blockDim.x + threadIdx.x;
  int stride = gridDim.x * blockDim.x;
  for (int j = i; j < NTOP * GPC; j += stride) {
    int col = j / GPC;
    int g = j - col * GPC;
    int k = g * 4;
    float4 v = make_float4(0.f, 0.f, 0.f, 0.f);
    if (k < VOCAB)
      v = *(const float4*)(beta + (u64)col * VOCAB + k);
    int kb = k >> 5;
    int jj = k & 31;
    int pbase = ((jj & 15) >> 2) * 8 + ((jj & 16) ? 4 : 0);
    u32 lo = pack2(v.x, v.y), hi = pack2(v.z, v.w);
    *(uint2*)(bp + (u64)kb * 2048 + col * 32 + pbase) = make_uint2(lo, hi);
  }
}

// Kernel 2: stream-friendly GEMM. 16 rows/block, KSPLIT=4 long chunks:
// 8192 streams of 50KB sequential, staged 1KB/row/instruction. A in small
// dbuf LDS (1 barrier/step); B read per-lane from L2-resident permuted bp.
// Wave w computes output cols [w*16, w*16+16) for all 16 rows.
__global__ void __launch_bounds__(256, 2) ctm_gemm(const float* __restrict__ x,
                                                   const u16* __restrict__ bp,
                                                   float* __restrict__ sp) {
  __shared__ u16 ldsA[2][16 * KSTEP];   // 8KB per buffer: [row][k] bf16,
                                        // byte = row*512 + (2k ^ ((row&7)<<4))
  const int t = threadIdx.x;
  const int l = t & 63;
  const int w = t >> 6;
  const int fr = l & 15;
  const int fk = l >> 4;

  const int bx = blockIdx.x;
  const int k0 = bx * CHUNKA;
  const int klen = (k0 + CHUNKA < VOCAB) ? CHUNKA : (VOCAB - k0);
  const int r0 = blockIdx.y * 16;

  // A staging: wave w stages rows w*4 .. w*4+3; per instruction ALL 64 lanes
  // read ONE row's 1KB contiguous (lane l -> float4 at l*4 floats).
  const float* xb = x + (u64)(r0 + w * 4) * VOCAB + k0 + l * 4;
  u32 wb[4];
  #pragma unroll
  for (int j = 0; j < 4; ++j) {
    const int row = w * 4 + j;
    wb[j] = (u32)(row * 512) + (((u32)(l * 8)) ^ ((u32)((row & 7) << 4)));
  }

  // B fragments: one 16B load per 32-k block, 1024B contiguous per wave-instr.
  const u16* bb = bp + (u64)(k0 >> 5) * 2048 + (w * 16 + fr) * 32 + fk * 8;

  // A fragment read constants
  const u32 arb = (u32)(fr * 512);
  const u32 aswz = (u32)((fr & 7) << 4);

  f32x4 acc = {0.f, 0.f, 0.f, 0.f};

  // ---- prologue: stage step 0 ----
  #pragma unroll
  for (int j = 0; j < 4; ++j) {
    float4 v = make_float4(0.f, 0.f, 0.f, 0.f);
    if (l * 4 < klen) v = *(const float4*)(xb + (u64)j * VOCAB);
    *(uint2*)((char*)ldsA[0] + wb[j]) = make_uint2(cvtpk(v.x, v.y), cvtpk(v.z, v.w));
  }
  __syncthreads();

  // ---- main loop: 1 barrier per 256-k step ----
  for (int st = 0; st < NSTEPS; ++st) {
    const int cb = st & 1;
    const bool have = (st + 1) < NSTEPS;

    // prefetch A(st+1) early
    float4 av[4];
    if (have) {
      const int rem = klen - (st + 1) * KSTEP;
      #pragma unroll
      for (int j = 0; j < 4; ++j) {
        av[j] = make_float4(0.f, 0.f, 0.f, 0.f);
        if (l * 4 < rem)
          av[j] = *(const float4*)(xb + (u64)j * VOCAB + (st + 1) * KSTEP);
      }
    }

    // compute current buffer: 8 x 32-k sub-steps, B straight from L2/L1
    const u16* bs = bb + (u64)st * 8 * 2048;
    const char* bufA = (const char*)ldsA[cb];
    #pragma unroll
    for (int s = 0; s < 8; ++s) {
      bf16x8 bfr = *(const bf16x8*)(bs + s * 2048);
      frag_cast ua;
      ua.h[0] = *(const bf16x4*)(bufA + arb + (((u32)(s * 64 + fk * 8)) ^ aswz));
      ua.h[1] = *(const bf16x4*)(bufA + arb + (((u32)(s * 64 + 32 + fk * 8)) ^ aswz));
      acc = __builtin_amdgcn_mfma_f32_16x16x32_bf16(ua.v, bfr, acc, 0, 0, 0);
    }

    // write A(st+1), single barrier
    if (have) {
      char* nA = (char*)ldsA[cb ^ 1];
      #pragma unroll
      for (int j = 0; j < 4; ++j)
        *(uint2*)(nA + wb[j]) = make_uint2(cvtpk(av[j].x, av[j].y), cvtpk(av[j].z, av[j].w));
      __syncthreads();
    }
  }

  // partials: sp[bx][r0 + fk*4 + r][w*16 + fr]  (C/D layout verified R1)
  float* spb = sp + (u64)bx * (BATCH * NTOP);
  #pragma unroll
  for (int r = 0; r < 4; ++r)
    spb[(u64)(r0 + fk * 4 + r) * NTOP + (w * 16 + fr)] = acc[r];
}

// Kernel 3: reduce KSPLIT partials, then out = s + mu + RHO*(s @ theta_offdiag^T)
__global__ void __launch_bounds__(256) ctm_epi(const float* __restrict__ sp,
                                               const float* __restrict__ theta,
                                               const float* __restrict__ mu,
                                               float* __restrict__ out) {
  __shared__ float thT[NTOP * NTOP];   // thT[j*64+k] = theta[k][j]
  __shared__ float sb[8 * NTOP];
  const int t = threadIdx.x;
  const int r0 = blockIdx.x * 8;

  #pragma unroll
  for (int i = 0; i < 16; ++i) {
    int e = i * 256 + t;
    thT[(e & 63) * 64 + (e >> 6)] = theta[e];
  }

  const int k = t & 63;
  const int rl = t >> 6;
  #pragma unroll
  for (int rr = 0; rr < 2; ++rr) {
    const int r = rl + rr * 4;
    float sum = 0.f;
    #pragma unroll
    for (int cc = 0; cc < KSPLIT; ++cc)
      sum += sp[(u64)cc * (BATCH * NTOP) + (r0 + r) * NTOP + k];
    sb[r * 64 + k] = sum;
  }
  __syncthreads();

  const float muk = mu[k];
  const float diag = thT[k * 64 + k];
  #pragma unroll
  for (int rr = 0; rr < 2; ++rr) {
    const int r = rl + rr * 4;
    const float* srow = &sb[r * 64];
    float accv = 0.f;
    #pragma unroll 8
    for (int j = 0; j < 64; ++j)
      accv += thT[j * 64 + k] * srow[j];
    const float sv = srow[k];
    out[(r0 + r) * 64 + k] = sv + muk + RHO * (accv - diag * sv);
  }
}

extern "C" void kernel_launch(void* const* d_in, const int* in_sizes, int n_in,
                              void* d_out, int out_size, void* d_ws, size_t ws_size,
                              hipStream_t stream) {
  const float* x = (const float*)d_in[0];
  const float* beta = (const float*)d_in[1];
  const float* theta = (const float*)d_in[2];
  const float* mu = (const float*)d_in[3];
  float* out = (float*)d_out;

  // ws: [0, 6422528) bp bf16 (NKB*2048*2B); then sp f32 [KSPLIT][BATCH][NTOP]
  // = 2MB. All of sp is written every launch; no zero-init needed.
  u16* bp = (u16*)d_ws;
  float* sp = (float*)((char*)d_ws + 6422528u);

  ctm_prep<<<1568, 256, 0, stream>>>(beta, bp);
  ctm_gemm<<<dim3(KSPLIT, BATCH / 16), 256, 0, stream>>>(x, bp, sp);
  ctm_epi<<<BATCH / 8, 256, 0, stream>>>(sp, theta, mu, out);
}

// Round 6
// 119.757 us; speedup vs baseline: 1.0276x; 1.0276x over previous
//
#include <hip/hip_runtime.h>

typedef unsigned short u16;
typedef unsigned int u32;
typedef unsigned long long u64;

#define VOCAB 50000
#define BATCH 2048
#define NTOP 64
#define RHO 0.1f

#define KSPLIT 32
#define CHUNK 1568          // 24x64+32; chunk 31: 48608..50000 = 21x64 + 48
#define KSTEP 64
#define NKB 1568            // bp 32-k blocks covering 50176 (zero-padded past 50000)
#define GPC 12544           // 50176/4 float4-groups per topic row

typedef short bf16x4 __attribute__((ext_vector_type(4)));
typedef short bf16x8 __attribute__((ext_vector_type(8)));
typedef float f32x4 __attribute__((ext_vector_type(4)));
typedef float f32x4v __attribute__((ext_vector_type(4)));

__device__ __forceinline__ u16 f32_to_bf16(float f) {
  u32 u = __builtin_bit_cast(u32, f);
  return (u16)((u + 0x8000u) >> 16);
}
__device__ __forceinline__ u32 pack2(float a, float b) {
  return (u32)f32_to_bf16(a) | ((u32)f32_to_bf16(b) << 16);
}
__device__ __forceinline__ u32 cvtpk(float lo, float hi) {
  u32 r;
  asm volatile("v_cvt_pk_bf16_f32 %0, %1, %2" : "=v"(r) : "v"(lo), "v"(hi));
  return r;
}
union frag_cast { bf16x4 h[2]; bf16x8 v; };

// Kernel 1: permute beta f32 -> bf16 MFMA-fragment order (R2/R5-proven):
// element(bp) = kb*2048 + col*32 + p;  p = fk*8 + e, e<4 -> k=kb*32+fk*4+e,
// e>=4 -> k=kb*32+16+fk*4+(e-4). Zero-padded for k in [50000, 50176).
__global__ void ctm_prep(const float* __restrict__ beta, u16* __restrict__ bp) {
  int i = blockIdx.x * blockDim.x + threadIdx.x;
  int stride = gridDim.x * blockDim.x;
  for (int j = i; j < NTOP * GPC; j += stride) {
    int col = j / GPC;
    int g = j - col * GPC;
    int k = g * 4;
    float4 v = make_float4(0.f, 0.f, 0.f, 0.f);
    if (k < VOCAB)
      v = *(const float4*)(beta + (u64)col * VOCAB + k);
    int kb = k >> 5;
    int jj = k & 31;
    int pbase = ((jj & 15) >> 2) * 8 + ((jj & 16) ? 4 : 0);
    u32 lo = pack2(v.x, v.y), hi = pack2(v.z, v.w);
    *(uint2*)(bp + (u64)kb * 2048 + col * 32 + pbase) = make_uint2(lo, hi);
  }
}

// Kernel 2: high-occupancy GEMM. 32-row blocks, KSPLIT=32 -> 2048 blocks,
// 6 blocks/CU. A: nt f32 loads -> cvt -> small dbuf LDS (1 barrier/step).
// B: per-lane 16B fragment loads from L2-resident permuted bp.
// Wave w: row-tile (w&1), col-tiles (w>>1)*2 + {0,1}.
__global__ void __launch_bounds__(256, 6) ctm_gemm(const float* __restrict__ x,
                                                   const u16* __restrict__ bp,
                                                   float* __restrict__ sp) {
  __shared__ u16 ldsA[2][32 * KSTEP];   // 4KB per buffer: [r][k] bf16,
                                        // byte = r*128 + (2k ^ ((r&7)<<4))
  const int t = threadIdx.x;
  const int l = t & 63;
  const int w = t >> 6;
  const int fr = l & 15;
  const int fk = l >> 4;

  const int bx = blockIdx.x;
  const int k0 = bx * CHUNK;
  const int kend = (k0 + CHUNK < VOCAB) ? (k0 + CHUNK) : VOCAB;
  const int row0 = blockIdx.y * 32;
  const int nsteps = (kend - k0 + KSTEP - 1) >> 6;

  // A staging: c = t&15 k-quad, srow = t>>4 handles rows {srow, srow+16}.
  // Per wave-instruction: 4 rows x 256B contiguous. Nontemporal (skip L2).
  const int c = t & 15;
  const int srow = t >> 4;
  const float* xb = x + (u64)(row0 + srow) * VOCAB + k0 + c * 4;
  const u32 wofs = (u32)(srow * 128) + (((u32)(c * 8)) ^ ((u32)((srow & 7) << 4)));

  // B fragment pointers: cols (w>>1)*32 + fr and +16
  const int col0 = (w >> 1) * 32 + fr;
  const u16* bb0 = bp + (u64)(k0 >> 5) * 2048 + col0 * 32 + fk * 8;
  const u16* bb1 = bb0 + 16 * 32;

  // A fragment read constants: row-tile w&1
  const int arow = (w & 1) * 16 + fr;
  const u32 arb = (u32)(arow * 128);
  const u32 aswz = (u32)((arow & 7) << 4);

  f32x4 acc0 = {0.f, 0.f, 0.f, 0.f};
  f32x4 acc1 = {0.f, 0.f, 0.f, 0.f};

  // ---- prologue: stage step 0 ----
  {
    const int rem = (kend - k0 < KSTEP) ? (kend - k0) : KSTEP;
    f32x4v a0 = {0.f,0.f,0.f,0.f}, a1 = {0.f,0.f,0.f,0.f};
    if (c * 4 < rem) {
      a0 = __builtin_nontemporal_load((const f32x4v*)xb);
      a1 = __builtin_nontemporal_load((const f32x4v*)(xb + 16 * VOCAB));
    }
    *(uint2*)((char*)ldsA[0] + wofs)        = make_uint2(cvtpk(a0.x, a0.y), cvtpk(a0.z, a0.w));
    *(uint2*)((char*)ldsA[0] + wofs + 2048) = make_uint2(cvtpk(a1.x, a1.y), cvtpk(a1.z, a1.w));
  }
  __syncthreads();

  // ---- main loop: 1 barrier per 64-k step ----
  for (int st = 0; st < nsteps; ++st) {
    const int cb = st & 1;
    const bool have = (st + 1) < nsteps;

    // 1) issue next step's nt loads early
    f32x4v a0 = {0.f,0.f,0.f,0.f}, a1 = {0.f,0.f,0.f,0.f};
    if (have) {
      const int rem = kend - k0 - ((st + 1) << 6);
      if (c * 4 < rem) {
        const float* xp = xb + ((st + 1) << 6);
        a0 = __builtin_nontemporal_load((const f32x4v*)xp);
        a1 = __builtin_nontemporal_load((const f32x4v*)(xp + 16 * VOCAB));
      }
    }

    // 2) compute current buffer: 2 x 32-k sub-steps
    const char* bufA = (const char*)ldsA[cb];
    #pragma unroll
    for (int s = 0; s < 2; ++s) {
      const u64 kb = (u64)(st * 2 + s) * 2048;
      bf16x8 b0 = *(const bf16x8*)(bb0 + kb);
      bf16x8 b1 = *(const bf16x8*)(bb1 + kb);
      const u32 in0 = (u32)(s * 64 + fk * 8);
      const u32 in1 = in0 + 32;
      frag_cast ua;
      ua.h[0] = *(const bf16x4*)(bufA + arb + (in0 ^ aswz));
      ua.h[1] = *(const bf16x4*)(bufA + arb + (in1 ^ aswz));
      acc0 = __builtin_amdgcn_mfma_f32_16x16x32_bf16(ua.v, b0, acc0, 0, 0, 0);
      acc1 = __builtin_amdgcn_mfma_f32_16x16x32_bf16(ua.v, b1, acc1, 0, 0, 0);
    }

    // 3) write next buffer, single barrier
    if (have) {
      char* nA = (char*)ldsA[cb ^ 1];
      *(uint2*)(nA + wofs)        = make_uint2(cvtpk(a0.x, a0.y), cvtpk(a0.z, a0.w));
      *(uint2*)(nA + wofs + 2048) = make_uint2(cvtpk(a1.x, a1.y), cvtpk(a1.z, a1.w));
      __syncthreads();
    }
  }

  // partials: sp[bx][row][col]; row = row0 + (w&1)*16 + fk*4 + r (C/D verified)
  float* spb = sp + (u64)bx * (BATCH * NTOP);
  const int orow = row0 + (w & 1) * 16 + fk * 4;
  #pragma unroll
  for (int r = 0; r < 4; ++r) {
    spb[(u64)(orow + r) * NTOP + col0] = acc0[r];
    spb[(u64)(orow + r) * NTOP + col0 + 16] = acc1[r];
  }
}

// Kernel 3: reduce 32 partials, then out = s + mu + RHO*(s @ theta_offdiag^T)
__global__ void __launch_bounds__(256) ctm_epi(const float* __restrict__ sp,
                                               const float* __restrict__ theta,
                                               const float* __restrict__ mu,
                                               float* __restrict__ out) {
  __shared__ float thT[NTOP * NTOP];   // thT[j*64+k] = theta[k][j]
  __shared__ float sb[8 * NTOP];
  const int t = threadIdx.x;
  const int r0 = blockIdx.x * 8;

  #pragma unroll
  for (int i = 0; i < 16; ++i) {
    int e = i * 256 + t;
    thT[(e & 63) * 64 + (e >> 6)] = theta[e];
  }

  const int k = t & 63;
  const int rl = t >> 6;
  #pragma unroll
  for (int rr = 0; rr < 2; ++rr) {
    const int r = rl + rr * 4;
    float sum = 0.f;
    #pragma unroll
    for (int cc = 0; cc < KSPLIT; ++cc)
      sum += sp[(u64)cc * (BATCH * NTOP) + (r0 + r) * NTOP + k];
    sb[r * 64 + k] = sum;
  }
  __syncthreads();

  const float muk = mu[k];
  const float diag = thT[k * 64 + k];
  #pragma unroll
  for (int rr = 0; rr < 2; ++rr) {
    const int r = rl + rr * 4;
    const float* srow = &sb[r * 64];
    float accv = 0.f;
    #pragma unroll 8
    for (int j = 0; j < 64; ++j)
      accv += thT[j * 64 + k] * srow[j];
    const float sv = srow[k];
    out[(r0 + r) * 64 + k] = sv + muk + RHO * (accv - diag * sv);
  }
}

extern "C" void kernel_launch(void* const* d_in, const int* in_sizes, int n_in,
                              void* d_out, int out_size, void* d_ws, size_t ws_size,
                              hipStream_t stream) {
  const float* x = (const float*)d_in[0];
  const float* beta = (const float*)d_in[1];
  const float* theta = (const float*)d_in[2];
  const float* mu = (const float*)d_in[3];
  float* out = (float*)d_out;

  // ws: [0, 6422528) bp bf16; then sp f32 [KSPLIT][BATCH][NTOP] = 16.8MB.
  // All of sp is written every launch; no zero-init needed.
  u16* bp = (u16*)d_ws;
  float* sp = (float*)((char*)d_ws + 6422528u);

  ctm_prep<<<1568, 256, 0, stream>>>(beta, bp);
  ctm_gemm<<<dim3(KSPLIT, BATCH / 32), 256, 0, stream>>>(x, bp, sp);
  ctm_epi<<<BATCH / 8, 256, 0, stream>>>(sp, theta, mu, out);
}

// Round 7
// 111.282 us; speedup vs baseline: 1.1058x; 1.0762x over previous
//
#include <hip/hip_runtime.h>
#include <hip/hip_fp16.h>

typedef unsigned short u16;
typedef unsigned int u32;
typedef unsigned long long u64;

#define VOCAB 50000
#define BATCH 2048
#define NTOP 64
#define RHO 0.1f

#define KSPLIT 24
#define CHUNK 2112          // 66*32; chunk 23: 48576..50000 = 44 full steps + 16 tail
#define KSTEP 32
#define BUFB 16384          // per-slot bytes: A 8KB + B 8KB (f32 tiles)

typedef short bf16x4 __attribute__((ext_vector_type(4)));
typedef short bf16x8 __attribute__((ext_vector_type(8)));
typedef float f32x4 __attribute__((ext_vector_type(4)));

__device__ __forceinline__ u32 cvtpk(float lo, float hi) {
  u32 r;
  asm volatile("v_cvt_pk_bf16_f32 %0, %1, %2" : "=v"(r) : "v"(lo), "v"(hi));
  return r;
}
union frag_cast { u32 w[4]; bf16x8 v; };

// GEMM: sp[bx] = x[rows, chunk bx] @ beta[:, chunk bx]^T, bf16 MFMA, f16 out.
// 3-slot LDS rotation fed by global_load_lds (direct DMA, f32 tiles), counted
// vmcnt(4) so 8 DMAs stay in flight across the single per-step barrier (T3/T4).
// LDS tile [r][k] f32, 128B/row, byte = r*128 + (off ^ ((r&7)<<4)); DMA dest is
// linear, so the XOR is applied to the per-lane GLOBAL source address instead
// (16B-granule involution, same line-set per wave -> still coalesced).
__global__ void __launch_bounds__(256, 3) ctm_gemm(const float* __restrict__ x,
                                                   const float* __restrict__ beta,
                                                   __half* __restrict__ sp) {
  __shared__ u16 lds[3 * BUFB / 2];

  const int t = threadIdx.x;
  const int l = t & 63;
  const int w = t >> 6;
  const int fr = l & 15;
  const int fk = l >> 4;

  const int bx = blockIdx.x;
  const int k0 = bx * CHUNK;
  const int kend = (k0 + CHUNK < VOCAB) ? (k0 + CHUNK) : VOCAB;
  const int row0 = blockIdx.y * 64;
  const int nfull = (kend - k0) >> 5;        // 66, or 44 on chunk 23
  const int rem = (kend - k0) & 31;          // 0, or 16 on chunk 23

  // --- staging addresses (DMA): thread t covers rows sr, sr+32; 16B granule so
  const int sr = t >> 3;                     // 0..31
  const int so = t & 7;
  const int swf = 4 * (so ^ (sr & 7));       // pre-swizzled float offset ((sr+32)&7 == sr&7)
  const float* xs0 = x + (u64)(row0 + sr) * VOCAB + k0 + swf;
  const float* xs1 = xs0 + (u64)32 * VOCAB;
  const float* bs0 = beta + (u64)sr * VOCAB + k0 + swf;
  const float* bs1 = bs0 + (u64)32 * VOCAB;
  const u32 dA0 = (u32)(t * 16), dA1 = dA0 + 4096;
  const u32 dB0 = dA0 + 8192,   dB1 = dA0 + 12288;

  // --- fragment-read constants: wave w owns rows w*16..+15, all 64 cols
  const int arow = w * 16 + fr;
  const u32 arb = (u32)(arow * 128);
  const u32 aswz = (u32)((arow & 7) << 4);
  const u32 aof0 = (u32)(fk * 16) ^ aswz;
  const u32 aof1 = (u32)(64 + fk * 16) ^ aswz;

  f32x4 acc[4] = {{0.f,0.f,0.f,0.f},{0.f,0.f,0.f,0.f},{0.f,0.f,0.f,0.f},{0.f,0.f,0.f,0.f}};

#define STAGE(slot, st)                                                          \
  {                                                                              \
    const u32 b_ = (u32)(slot) * BUFB;                                           \
    const u64 ko_ = (u64)((st) * KSTEP);                                         \
    __builtin_amdgcn_global_load_lds(                                            \
        (const __attribute__((address_space(1))) void*)(xs0 + ko_),              \
        (__attribute__((address_space(3))) void*)((char*)lds + b_ + dA0), 16, 0, 0); \
    __builtin_amdgcn_global_load_lds(                                            \
        (const __attribute__((address_space(1))) void*)(xs1 + ko_),              \
        (__attribute__((address_space(3))) void*)((char*)lds + b_ + dA1), 16, 0, 0); \
    __builtin_amdgcn_global_load_lds(                                            \
        (const __attribute__((address_space(1))) void*)(bs0 + ko_),              \
        (__attribute__((address_space(3))) void*)((char*)lds + b_ + dB0), 16, 0, 0); \
    __builtin_amdgcn_global_load_lds(                                            \
        (const __attribute__((address_space(1))) void*)(bs1 + ko_),              \
        (__attribute__((address_space(3))) void*)((char*)lds + b_ + dB1), 16, 0, 0); \
  }

#define COMPUTE(slot)                                                            \
  {                                                                              \
    const char* bufA = (const char*)lds + (u32)(slot) * BUFB;                    \
    const char* bufB = bufA + 8192;                                              \
    f32x4 q0 = *(const f32x4*)(bufA + arb + aof0);                               \
    f32x4 q1 = *(const f32x4*)(bufA + arb + aof1);                               \
    frag_cast ua;                                                                \
    ua.w[0] = cvtpk(q0.x, q0.y); ua.w[1] = cvtpk(q0.z, q0.w);                    \
    ua.w[2] = cvtpk(q1.x, q1.y); ua.w[3] = cvtpk(q1.z, q1.w);                    \
    _Pragma("unroll")                                                            \
    for (int n = 0; n < 4; ++n) {                                                \
      const int bcol = n * 16 + fr;                                              \
      const u32 brb = (u32)(bcol * 128);                                         \
      const u32 bswz = (u32)((bcol & 7) << 4);                                   \
      f32x4 p0 = *(const f32x4*)(bufB + brb + (((u32)(fk * 16)) ^ bswz));        \
      f32x4 p1 = *(const f32x4*)(bufB + brb + (((u32)(64 + fk * 16)) ^ bswz));   \
      frag_cast ub;                                                              \
      ub.w[0] = cvtpk(p0.x, p0.y); ub.w[1] = cvtpk(p0.z, p0.w);                  \
      ub.w[2] = cvtpk(p1.x, p1.y); ub.w[3] = cvtpk(p1.z, p1.w);                  \
      acc[n] = __builtin_amdgcn_mfma_f32_16x16x32_bf16(ua.v, ub.v, acc[n], 0, 0, 0); \
    }                                                                            \
  }

  // prologue: fill slots 0,1 (nfull >= 44 always)
  STAGE(0, 0);
  STAGE(1, 1);

  int slot = 0;
  for (int st = 0; st < nfull; ++st) {
    if (st + 1 < nfull) asm volatile("s_waitcnt vmcnt(4)" ::: "memory");
    else                asm volatile("s_waitcnt vmcnt(0)" ::: "memory");
    __builtin_amdgcn_s_barrier();
    __builtin_amdgcn_sched_barrier(0);
    if (st + 2 < nfull) {
      const int ns = (slot + 2 >= 3) ? (slot - 1) : (slot + 2);
      STAGE(ns, st + 2);
    }
    COMPUTE(slot);
    slot = (slot + 1 >= 3) ? 0 : slot + 1;
  }

  // tail (chunk 23 only; block-uniform): 16 valid k, reg-staged + zero-padded
  if (rem) {
    const int trow = t >> 2;
    const int tq = t & 3;                    // 8-float group
    const int ktail = k0 + nfull * KSTEP;
    const u32 wofs = (u32)(trow * 128) + (((u32)(tq * 32)) ^ ((u32)((trow & 7) << 4)));
    float4 va0 = make_float4(0,0,0,0), va1 = va0, vb0 = va0, vb1 = va0;
    if (tq * 8 < rem) {                      // rem==16: tq 0,1 fully valid
      const float* xp = x + (u64)(row0 + trow) * VOCAB + ktail + tq * 8;
      const float* bp2 = beta + (u64)trow * VOCAB + ktail + tq * 8;
      va0 = *(const float4*)xp;  va1 = *(const float4*)(xp + 4);
      vb0 = *(const float4*)bp2; vb1 = *(const float4*)(bp2 + 4);
    }
    char* tb = (char*)lds + (u32)slot * BUFB;
    uint4 pa, pb;
    pa.x = cvtpk(va0.x, va0.y); pa.y = cvtpk(va0.z, va0.w);
    pa.z = cvtpk(va1.x, va1.y); pa.w = cvtpk(va1.z, va1.w);
    pb.x = cvtpk(vb0.x, vb0.y); pb.y = cvtpk(vb0.z, vb0.w);
    pb.z = cvtpk(vb1.x, vb1.y); pb.w = cvtpk(vb1.z, vb1.w);
    // tail tile is bf16-packed into f32-slot positions? No: keep f32 semantics —
    // write raw floats so COMPUTE's cvt path stays identical.
    *(float4*)(tb + trow * 128 + (((u32)(tq * 32)) ^ ((u32)((trow & 7) << 4)))) =
        (tq * 8 < rem) ? va0 : make_float4(0,0,0,0);
    (void)wofs; (void)pa; (void)pb;
    // second 16B of the 32B group
    *(float4*)(tb + trow * 128 + (((u32)(tq * 32 + 16)) ^ ((u32)((trow & 7) << 4)))) =
        (tq * 8 < rem) ? va1 : make_float4(0,0,0,0);
    *(float4*)(tb + 8192 + trow * 128 + (((u32)(tq * 32)) ^ ((u32)((trow & 7) << 4)))) =
        (tq * 8 < rem) ? vb0 : make_float4(0,0,0,0);
    *(float4*)(tb + 8192 + trow * 128 + (((u32)(tq * 32 + 16)) ^ ((u32)((trow & 7) << 4)))) =
        (tq * 8 < rem) ? vb1 : make_float4(0,0,0,0);
    __syncthreads();
    COMPUTE(slot);
  }

  // C-write: f16 partials; row = w*16 + fk*4 + r, col = n*16 + fr
  __half* spb = sp + (u64)bx * (BATCH * NTOP);
  const int orow = row0 + w * 16 + fk * 4;
  #pragma unroll
  for (int n = 0; n < 4; ++n) {
    #pragma unroll
    for (int r = 0; r < 4; ++r)
      spb[(u64)(orow + r) * NTOP + (n * 16 + fr)] = __float2half(acc[n][r]);
  }
#undef STAGE
#undef COMPUTE
}

// Epilogue: reduce 24 f16 partials, then out = s + mu + RHO*(s @ theta_offdiag^T)
__global__ void __launch_bounds__(256) ctm_epi(const __half* __restrict__ sp,
                                               const float* __restrict__ theta,
                                               const float* __restrict__ mu,
                                               float* __restrict__ out) {
  __shared__ float thT[NTOP * NTOP];   // thT[j*64+k] = theta[k][j]
  __shared__ float sb[8 * NTOP];
  const int t = threadIdx.x;
  const int r0 = blockIdx.x * 8;

  #pragma unroll
  for (int i = 0; i < 16; ++i) {
    int e = i * 256 + t;
    thT[(e & 63) * 64 + (e >> 6)] = theta[e];
  }

  const int k = t & 63;
  const int rl = t >> 6;
  #pragma unroll
  for (int rr = 0; rr < 2; ++rr) {
    const int r = rl + rr * 4;
    float sum = 0.f;
    #pragma unroll
    for (int cc = 0; cc < KSPLIT; ++cc)
      sum += __half2float(sp[(u64)cc * (BATCH * NTOP) + (u64)(r0 + r) * NTOP + k]);
    sb[r * 64 + k] = sum;
  }
  __syncthreads();

  const float muk = mu[k];
  const float diag = thT[k * 64 + k];
  #pragma unroll
  for (int rr = 0; rr < 2; ++rr) {
    const int r = rl + rr * 4;
    const float* srow = &sb[r * 64];
    float accv = 0.f;
    #pragma unroll 8
    for (int j = 0; j < 64; ++j)
      accv += thT[j * 64 + k] * srow[j];
    const float sv = srow[k];
    out[(r0 + r) * 64 + k] = sv + muk + RHO * (accv - diag * sv);
  }
}

extern "C" void kernel_launch(void* const* d_in, const int* in_sizes, int n_in,
                              void* d_out, int out_size, void* d_ws, size_t ws_size,
                              hipStream_t stream) {
  const float* x = (const float*)d_in[0];
  const float* beta = (const float*)d_in[1];
  const float* theta = (const float*)d_in[2];
  const float* mu = (const float*)d_in[3];
  float* out = (float*)d_out;

  // ws: sp f16 [KSPLIT][BATCH][NTOP] = 6.29MB; fully written each launch.
  __half* sp = (__half*)d_ws;

  ctm_gemm<<<dim3(KSPLIT, BATCH / 64), 256, 0, stream>>>(x, beta, sp);
  ctm_epi<<<BATCH / 8, 256, 0, stream>>>(sp, theta, mu, out);
}

// Round 9
// 101.518 us; speedup vs baseline: 1.2122x; 1.0962x over previous
//
#include <hip/hip_runtime.h>
#include <hip/hip_fp16.h>

typedef unsigned short u16;
typedef unsigned int u32;
typedef unsigned long long u64;

#define VOCAB 50000
#define BATCH 2048
#define NTOP 64
#define RHO 0.1f

#define KSPLIT 32
#define CHUNK 1568          // 24x64+32; chunk 31: 48608..50000 = 21x64 + 48
#define KSTEP 64

typedef short bf16x4 __attribute__((ext_vector_type(4)));
typedef short bf16x8 __attribute__((ext_vector_type(8)));
typedef float f32x4 __attribute__((ext_vector_type(4)));

__device__ __forceinline__ u32 cvtpk(float lo, float hi) {
  u32 r;
  asm volatile("v_cvt_pk_bf16_f32 %0, %1, %2" : "=v"(r) : "v"(lo), "v"(hi));
  return r;
}
union frag_cast { bf16x4 h[2]; bf16x8 v; };

// GEMM (R4 structure + 2-deep x prefetch + f16 partials):
// sp[bx] = x[rows, chunk bx] @ beta[:, chunk bx]^T via bf16 MFMA.
// x: TWO register sets (xA*/xB*), each 4 float4 -> 16 x-loads in flight per
//    wave (2 k-steps ahead) to deepen HBM queue occupancy.
// beta: 1-deep reg staging (L2-resident; chunk bx's 32 row-blocks land on
//    XCD bx%8, so beta is HBM-fetched once per chunk).
// LDS [r][k] bf16 dbuf, byte = r*128 + (2k ^ ((r&7)<<4)); 1 barrier/step.
__global__ void __launch_bounds__(256, 4) ctm_gemm(const float* __restrict__ x,
                                                   const float* __restrict__ beta,
                                                   __half* __restrict__ sp) {
  __shared__ u16 ldsX[2][64 * KSTEP];   // 8KB per buffer
  __shared__ u16 ldsB[2][64 * KSTEP];

  const int t = threadIdx.x;
  const int l = t & 63;
  const int w = t >> 6;
  const int fr = l & 15;
  const int fk = l >> 4;

  const int bx = blockIdx.x;
  const int k0 = bx * CHUNK;
  const int kend = (k0 + CHUNK < VOCAB) ? (k0 + CHUNK) : VOCAB;
  const int row0 = blockIdx.y * 64;
  const int nsteps = (kend - k0 + KSTEP - 1) >> 6;   // 25, or 22 on chunk 31

  // Staging map: c = t&15 k-quad, srow = t>>4 covers rows {srow,+16,+32,+48}.
  const int c = t & 15;
  const int srow = t >> 4;
  const float* xb = x + (u64)(row0 + srow) * VOCAB + k0 + c * 4;
  const float* betab = beta + (u64)srow * VOCAB + k0 + c * 4;
  const u32 wofs = (u32)(srow * 128) + (((u32)(c * 8)) ^ ((u32)((srow & 7) << 4)));

  // Fragment-read constants
  const int arow = w * 16 + fr;
  const u32 arb = (u32)(arow * 128);
  const u32 aswz = (u32)((arow & 7) << 4);

  f32x4 acc[4] = {{0.f,0.f,0.f,0.f},{0.f,0.f,0.f,0.f},{0.f,0.f,0.f,0.f},{0.f,0.f,0.f,0.f}};

  float4 xA0, xA1, xA2, xA3, xB0, xB1, xB2, xB3;   // 2-deep x sets
  float4 bb0, bb1, bb2, bb3;                        // 1-deep beta set

#define LOADX(S0, S1, S2, S3, st)                                            \
  {                                                                          \
    const int rem_ = kend - k0 - (st) * KSTEP;                               \
    S0 = S1 = S2 = S3 = make_float4(0.f, 0.f, 0.f, 0.f);                     \
    if (c * 4 < rem_) {                                                      \
      const float* p_ = xb + (st) * KSTEP;                                   \
      S0 = *(const float4*)(p_);                                             \
      S1 = *(const float4*)(p_ + 16 * VOCAB);                                \
      S2 = *(const float4*)(p_ + 32 * VOCAB);                                \
      S3 = *(const float4*)(p_ + 48 * VOCAB);                                \
    }                                                                        \
  }

#define LOADB(st)                                                            \
  {                                                                          \
    const int rem_ = kend - k0 - (st) * KSTEP;                               \
    bb0 = bb1 = bb2 = bb3 = make_float4(0.f, 0.f, 0.f, 0.f);                 \
    if (c * 4 < rem_) {                                                      \
      const float* p_ = betab + (st) * KSTEP;                                \
      bb0 = *(const float4*)(p_);                                            \
      bb1 = *(const float4*)(p_ + 16 * VOCAB);                               \
      bb2 = *(const float4*)(p_ + 32 * VOCAB);                               \
      bb3 = *(const float4*)(p_ + 48 * VOCAB);                               \
    }                                                                        \
  }

#define WRITE(S0, S1, S2, S3, bi)                                            \
  {                                                                          \
    char* nX = (char*)ldsX[bi];                                              \
    char* nB = (char*)ldsB[bi];                                              \
    *(uint2*)(nX + wofs)        = make_uint2(cvtpk(S0.x, S0.y), cvtpk(S0.z, S0.w)); \
    *(uint2*)(nX + wofs + 2048) = make_uint2(cvtpk(S1.x, S1.y), cvtpk(S1.z, S1.w)); \
    *(uint2*)(nX + wofs + 4096) = make_uint2(cvtpk(S2.x, S2.y), cvtpk(S2.z, S2.w)); \
    *(uint2*)(nX + wofs + 6144) = make_uint2(cvtpk(S3.x, S3.y), cvtpk(S3.z, S3.w)); \
    *(uint2*)(nB + wofs)        = make_uint2(cvtpk(bb0.x, bb0.y), cvtpk(bb0.z, bb0.w)); \
    *(uint2*)(nB + wofs + 2048) = make_uint2(cvtpk(bb1.x, bb1.y), cvtpk(bb1.z, bb1.w)); \
    *(uint2*)(nB + wofs + 4096) = make_uint2(cvtpk(bb2.x, bb2.y), cvtpk(bb2.z, bb2.w)); \
    *(uint2*)(nB + wofs + 6144) = make_uint2(cvtpk(bb3.x, bb3.y), cvtpk(bb3.z, bb3.w)); \
  }

#define COMPUTE(bi)                                                          \
  {                                                                          \
    const char* bufA = (const char*)ldsX[bi];                                \
    const char* bufB = (const char*)ldsB[bi];                                \
    _Pragma("unroll")                                                        \
    for (int s_ = 0; s_ < 2; ++s_) {                                         \
      const u32 in0 = (u32)(s_ * 64 + fk * 8);                               \
      const u32 in1 = in0 + 32;                                              \
      frag_cast ua;                                                          \
      ua.h[0] = *(const bf16x4*)(bufA + arb + (in0 ^ aswz));                 \
      ua.h[1] = *(const bf16x4*)(bufA + arb + (in1 ^ aswz));                 \
      _Pragma("unroll")                                                      \
      for (int n_ = 0; n_ < 4; ++n_) {                                       \
        const int bcol = (n_ << 4) | fr;                                     \
        const u32 brb = (u32)(bcol * 128);                                   \
        const u32 bswz = (u32)((bcol & 7) << 4);                             \
        frag_cast ub;                                                        \
        ub.h[0] = *(const bf16x4*)(bufB + brb + (in0 ^ bswz));               \
        ub.h[1] = *(const bf16x4*)(bufB + brb + (in1 ^ bswz));               \
        acc[n_] = __builtin_amdgcn_mfma_f32_16x16x32_bf16(ua.v, ub.v, acc[n_], 0, 0, 0); \
      }                                                                      \
    }                                                                        \
  }

  // ---- prologue: stage step 0; preload x for steps 1 (xA) and 2 (xB) ----
  LOADX(xA0, xA1, xA2, xA3, 0);
  LOADB(0);
  WRITE(xA0, xA1, xA2, xA3, 0);
  LOADX(xA0, xA1, xA2, xA3, 1);
  LOADX(xB0, xB1, xB2, xB3, 2);
  __syncthreads();

  // ---- main loop: phases alternate x-set A/B; 1 barrier per step ----
  // invariant at phase start for step st: the x-set of parity (st+1)&1
  // (A on even st, B on odd) holds step st+1's data.
  int st = 0;
  while (true) {
    // phase A (even st)
    if (st + 1 < nsteps) LOADB(st + 1);
    COMPUTE(st & 1);
    if (st + 1 < nsteps) WRITE(xA0, xA1, xA2, xA3, (st + 1) & 1);
    if (st + 3 < nsteps) LOADX(xA0, xA1, xA2, xA3, st + 3);
    if (st + 1 < nsteps) __syncthreads();
    if (++st >= nsteps) break;

    // phase B (odd st)
    if (st + 1 < nsteps) LOADB(st + 1);
    COMPUTE(st & 1);
    if (st + 1 < nsteps) WRITE(xB0, xB1, xB2, xB3, (st + 1) & 1);
    if (st + 3 < nsteps) LOADX(xB0, xB1, xB2, xB3, st + 3);
    if (st + 1 < nsteps) __syncthreads();
    if (++st >= nsteps) break;
  }

  // C-write: f16 partials; row = w*16 + fk*4 + r, col = n*16 + fr
  __half* spb = sp + (u64)bx * (BATCH * NTOP);
  const int orow = row0 + w * 16 + fk * 4;
  #pragma unroll
  for (int n = 0; n < 4; ++n) {
    #pragma unroll
    for (int r = 0; r < 4; ++r)
      spb[(u64)(orow + r) * NTOP + ((n << 4) | fr)] = __float2half(acc[n][r]);
  }
#undef LOADX
#undef LOADB
#undef WRITE
#undef COMPUTE
}

// Epilogue: reduce 32 f16 partials, then out = s + mu + RHO*(s @ theta_offdiag^T)
__global__ void __launch_bounds__(256) ctm_epi(const __half* __restrict__ sp,
                                               const float* __restrict__ theta,
                                               const float* __restrict__ mu,
                                               float* __restrict__ out) {
  __shared__ float thT[NTOP * NTOP];   // thT[j*64+k] = theta[k][j]
  __shared__ float sb[8 * NTOP];
  const int t = threadIdx.x;
  const int r0 = blockIdx.x * 8;

  #pragma unroll
  for (int i = 0; i < 16; ++i) {
    int e = i * 256 + t;
    thT[(e & 63) * 64 + (e >> 6)] = theta[e];
  }

  const int k = t & 63;
  const int rl = t >> 6;
  #pragma unroll
  for (int rr = 0; rr < 2; ++rr) {
    const int r = rl + rr * 4;
    float sum = 0.f;
    #pragma unroll
    for (int cc = 0; cc < KSPLIT; ++cc)
      sum += __half2float(sp[(u64)cc * (BATCH * NTOP) + (u64)(r0 + r) * NTOP + k]);
    sb[r * 64 + k] = sum;
  }
  __syncthreads();

  const float muk = mu[k];
  const float diag = thT[k * 64 + k];
  #pragma unroll
  for (int rr = 0; rr < 2; ++rr) {
    const int r = rl + rr * 4;
    const float* srow = &sb[r * 64];
    float accv = 0.f;
    #pragma unroll 8
    for (int j = 0; j < 64; ++j)
      accv += thT[j * 64 + k] * srow[j];
    const float sv = srow[k];
    out[(r0 + r) * 64 + k] = sv + muk + RHO * (accv - diag * sv);
  }
}

extern "C" void kernel_launch(void* const* d_in, const int* in_sizes, int n_in,
                              void* d_out, int out_size, void* d_ws, size_t ws_size,
                              hipStream_t stream) {
  const float* x = (const float*)d_in[0];
  const float* beta = (const float*)d_in[1];
  const float* theta = (const float*)d_in[2];
  const float* mu = (const float*)d_in[3];
  float* out = (float*)d_out;

  // ws: sp f16 [KSPLIT][BATCH][NTOP] = 8.39MB; fully written each launch.
  __half* sp = (__half*)d_ws;

  ctm_gemm<<<dim3(KSPLIT, BATCH / 64), 256, 0, stream>>>(x, beta, sp);
  ctm_epi<<<BATCH / 8, 256, 0, stream>>>(sp, theta, mu, out);
}